// Round 16
// baseline (132.802 us; speedup 1.0000x reference)
//
#include <hip/hip_runtime.h>
#include <stdint.h>

// Problem constants: B=2, S=2048, D=1024, H=16, DH=64
#define SB 2
#define SS 2048
#define SD 1024
#define SH 16
#define SDH 64
#define SM (SB*SS)          // 4096 rows
// Q pre-scale: (1/sqrt(DH)) * log2(e) = 0.125 * 1.4426950408889634
#define QSCALE 0.18033688011112043f

typedef __attribute__((ext_vector_type(8))) short short8;
typedef __attribute__((ext_vector_type(4))) short short4v;
typedef __attribute__((ext_vector_type(4))) float f32x4;
typedef __attribute__((ext_vector_type(4))) float float4v;
typedef __attribute__((ext_vector_type(4))) uint32_t uint4v;
typedef __attribute__((ext_vector_type(2))) unsigned long long ull2;

__device__ static inline short f2bf(float f) {
    uint32_t u = __float_as_uint(f);
    u += 0x7fffu + ((u >> 16) & 1u);   // RNE
    return (short)(u >> 16);
}

__device__ static inline void gload_lds16(const void* g, void* l) {
    __builtin_amdgcn_global_load_lds(
        (__attribute__((address_space(1))) void*)g,
        (__attribute__((address_space(3))) void*)l,
        16, 0, 0);
}

// ---------------- fused prep: fp32->bf16 convert (x + 4 weights) AND mask bit-pack ----------------
#define NX4 (SM*SD/4)      // 1048576 float4 in x
#define NW4 (SD*SD/4)      // 262144 float4 per weight
#define NCVT (NX4 + 4*NW4) // 2097152 cvt threads
#define NMSK (SB*SS*SS)    // 8388608 mask threads
__global__ void prep_kernel(const float* __restrict__ x,
                            const float* __restrict__ Wq, const float* __restrict__ Wk,
                            const float* __restrict__ Wv, const float* __restrict__ Wo,
                            const int* __restrict__ mask,
                            short* __restrict__ xb,
                            short* __restrict__ wqb, short* __restrict__ wkb,
                            short* __restrict__ wvb, short* __restrict__ wob,
                            unsigned long long* __restrict__ bits) {
    unsigned i = blockIdx.x * 256u + threadIdx.x;
    if (i < NCVT) {
        const float* src; short* dst; unsigned idx;
        if (i < NX4) { src = x; dst = xb; idx = i; }
        else {
            unsigned j = i - NX4;
            unsigned sel = j >> 18;               // NW4 = 2^18
            idx = j & (NW4 - 1);
            src = (sel == 0) ? Wq : (sel == 1) ? Wk : (sel == 2) ? Wv : Wo;
            dst = (sel == 0) ? wqb : (sel == 1) ? wkb : (sel == 2) ? wvb : wob;
        }
        float4v v = *(const float4v*)(src + (size_t)idx * 4);
        short4v o;
        o[0] = f2bf(v[0]); o[1] = f2bf(v[1]); o[2] = f2bf(v[2]); o[3] = f2bf(v[3]);
        *(short4v*)(dst + (size_t)idx * 4) = o;
    } else {
        unsigned j = i - NCVT;                    // wave-aligned region (NCVT % 64 == 0)
        int pred = mask[j] != 0;
        unsigned long long bb = __ballot(pred);
        if ((threadIdx.x & 63u) == 0u) bits[j >> 6] = bb;
    }
}

// ---------------- QKV GEMM: 128x128 tile, BK=32, 2-phase pipeline, XCD-swizzled ----------------
// R15: __launch_bounds__(256,4) -> permit 4 blocks/CU (16 waves) for deeper barrier overlap.
__global__ __launch_bounds__(256, 4) void gemm_qkv_kernel(
    const short* __restrict__ A,
    const short* __restrict__ W0, const short* __restrict__ W1, const short* __restrict__ W2,
    const float* __restrict__ b0, const float* __restrict__ b1, const float* __restrict__ b2,
    short* __restrict__ O0, short* __restrict__ O1, short* __restrict__ O2) {
    // grid (8,32,3) = 768 blocks; bijective XCD swizzle: each XCD gets 96 consecutive logicals
    unsigned flat = blockIdx.x + (blockIdx.y << 3) + (blockIdx.z << 8);
    unsigned swz = (flat & 7u) * 96u + (flat >> 3);
    const int bx = swz & 7, by = (swz >> 3) & 31, bz = swz >> 8;

    const short* W = (bz == 0) ? W0 : (bz == 1) ? W1 : W2;
    const float* bias = (bz == 0) ? b0 : (bz == 1) ? b1 : b2;
    short* C = (bz == 0) ? O0 : (bz == 1) ? O1 : O2;
    const float scale = (bz == 0) ? QSCALE : 1.0f;
    const int rowBase = by * 128, colBase = bx * 128;
    const int K = SD, N = SD;

    __shared__ short As[2][128 * 32];
    __shared__ short Bs[2][128 * 32];
    const int tid = threadIdx.x, lane = tid & 63, wid = tid >> 6;
    const int r15 = lane & 15, hi = lane >> 4;
    const int wr = wid >> 1, wc = wid & 1;

    const int chBase0 = wid * 64, chBase1 = 256 + wid * 64;
    const int ch0 = chBase0 + lane, ch1 = chBase1 + lane;
    const short* aP0 = A + (size_t)(rowBase + (ch0 >> 2)) * K + (ch0 & 3) * 8;
    const short* aP1 = A + (size_t)(rowBase + (ch1 >> 2)) * K + (ch1 & 3) * 8;
    const short* bP0 = W + (size_t)(colBase + (ch0 >> 2)) * K + (ch0 & 3) * 8;
    const short* bP1 = W + (size_t)(colBase + (ch1 >> 2)) * K + (ch1 & 3) * 8;

    gload_lds16(aP0, &As[0][chBase0 * 8]);
    gload_lds16(aP1, &As[0][chBase1 * 8]);
    gload_lds16(bP0, &Bs[0][chBase0 * 8]);
    gload_lds16(bP1, &Bs[0][chBase1 * 8]);

    f32x4 acc[4][4] = {};
    const int NIT = K / 32;

    for (int it = 0; it < NIT; ++it) {
        __syncthreads();
        const int cur = it & 1, nxt = cur ^ 1;
        if (it + 1 < NIT) {
            int kt = (it + 1) * 32;
            gload_lds16(aP0 + kt, &As[nxt][chBase0 * 8]);
            gload_lds16(aP1 + kt, &As[nxt][chBase1 * 8]);
            gload_lds16(bP0 + kt, &Bs[nxt][chBase0 * 8]);
            gload_lds16(bP1 + kt, &Bs[nxt][chBase1 * 8]);
        }

        short8 aF[4], bF[4];
#pragma unroll
        for (int mi = 0; mi < 4; ++mi)
            aF[mi] = *(const short8*)&As[cur][(wr * 64 + mi * 16 + r15) * 32 + hi * 8];
#pragma unroll
        for (int ni = 0; ni < 4; ++ni)
            bF[ni] = *(const short8*)&Bs[cur][(wc * 64 + ni * 16 + r15) * 32 + hi * 8];

        __builtin_amdgcn_s_setprio(1);
#pragma unroll
        for (int mi = 0; mi < 4; ++mi)
#pragma unroll
            for (int ni = 0; ni < 4; ++ni)
                acc[mi][ni] = __builtin_amdgcn_mfma_f32_16x16x32_bf16(aF[mi], bF[ni], acc[mi][ni], 0, 0, 0);
        __builtin_amdgcn_s_setprio(0);
    }

#pragma unroll
    for (int ni = 0; ni < 4; ++ni) {
        int col = colBase + wc * 64 + ni * 16 + r15;
        float bv = bias[col];
#pragma unroll
        for (int mi = 0; mi < 4; ++mi) {
#pragma unroll
            for (int r = 0; r < 4; ++r) {
                int row = rowBase + wr * 64 + mi * 16 + hi * 4 + r;
                C[(size_t)row * N + col] = f2bf((acc[mi][ni][r] + bv) * scale);
            }
        }
    }
}

// ---------------- out-proj GEMM: 128x64 tile, grid (16,32) = 512 blocks, XCD-swizzled ----------------
__global__ __launch_bounds__(256, 2) void gemm_out_kernel(
    const short* __restrict__ A, const short* __restrict__ W,
    const float* __restrict__ bias, float* __restrict__ C) {
    unsigned flat = blockIdx.x + (blockIdx.y << 4);
    unsigned swz = (flat & 7u) * 64u + (flat >> 3);
    const int rowBase = ((swz >> 4) & 31) * 128, colBase = (swz & 15) * 64;
    const int K = SD, N = SD;

    __shared__ short As[2][128 * 32];
    __shared__ short Bs[2][64 * 32];
    const int tid = threadIdx.x, lane = tid & 63, wid = tid >> 6;
    const int r15 = lane & 15, hi = lane >> 4;

    const int chBase0 = wid * 64, chBase1 = 256 + wid * 64;
    const int ch0 = chBase0 + lane, ch1 = chBase1 + lane;
    const short* aP0 = A + (size_t)(rowBase + (ch0 >> 2)) * K + (ch0 & 3) * 8;
    const short* aP1 = A + (size_t)(rowBase + (ch1 >> 2)) * K + (ch1 & 3) * 8;
    const short* bP0 = W + (size_t)(colBase + (ch0 >> 2)) * K + (ch0 & 3) * 8;

    gload_lds16(aP0, &As[0][chBase0 * 8]);
    gload_lds16(aP1, &As[0][chBase1 * 8]);
    gload_lds16(bP0, &Bs[0][chBase0 * 8]);

    f32x4 acc[2][4] = {};
    const int NIT = K / 32;

    for (int it = 0; it < NIT; ++it) {
        __syncthreads();
        const int cur = it & 1, nxt = cur ^ 1;
        if (it + 1 < NIT) {
            int kt = (it + 1) * 32;
            gload_lds16(aP0 + kt, &As[nxt][chBase0 * 8]);
            gload_lds16(aP1 + kt, &As[nxt][chBase1 * 8]);
            gload_lds16(bP0 + kt, &Bs[nxt][chBase0 * 8]);
        }

        short8 aF[2], bF[4];
#pragma unroll
        for (int mi = 0; mi < 2; ++mi)
            aF[mi] = *(const short8*)&As[cur][(wid * 32 + mi * 16 + r15) * 32 + hi * 8];
#pragma unroll
        for (int ni = 0; ni < 4; ++ni)
            bF[ni] = *(const short8*)&Bs[cur][(ni * 16 + r15) * 32 + hi * 8];

        __builtin_amdgcn_s_setprio(1);
#pragma unroll
        for (int mi = 0; mi < 2; ++mi)
#pragma unroll
            for (int ni = 0; ni < 4; ++ni)
                acc[mi][ni] = __builtin_amdgcn_mfma_f32_16x16x32_bf16(aF[mi], bF[ni], acc[mi][ni], 0, 0, 0);
        __builtin_amdgcn_s_setprio(0);
    }

#pragma unroll
    for (int ni = 0; ni < 4; ++ni) {
        int col = colBase + ni * 16 + r15;
        float bv = bias[col];
#pragma unroll
        for (int mi = 0; mi < 2; ++mi) {
#pragma unroll
            for (int r = 0; r < 4; ++r) {
                int row = rowBase + wid * 32 + mi * 16 + hi * 4 + r;
                C[(size_t)row * N + col] = acc[mi][ni][r] + bv;
            }
        }
    }
}

// ---------------- flash attention (R12: KVBLK=128, 16q/wave, 2 blocks/CU) ----------------
// grid (S/128, H, B) = 512 blocks (2/CU); block 512 = 8 waves; wave owns 16 q rows.
// KV processed 128 rows per iteration (16 loop iters, 16 barriers). Shift-free softmax,
// sign-extend masking, in-register P via permuted contraction (V cols at
// c(k)=(k&96)|((k&12)<<1)|((k&16)>>2)|(k&3)), XCD swizzle for L2-hot K/V.
__global__ __launch_bounds__(512, 4) void attn_kernel(
    const short* __restrict__ Q, const short* __restrict__ K, const short* __restrict__ V,
    const unsigned long long* __restrict__ mbits, short* __restrict__ O) {
    // grid (16,16,2) = 512 blocks; bijective swizzle: XCD k gets 64 consecutive logicals
    unsigned flat = blockIdx.x + (blockIdx.y << 4) + (blockIdx.z << 8);
    unsigned swz = (flat & 7u) * 64u + (flat >> 3);
    const int bx = swz & 15, h = (swz >> 4) & 15, b = swz >> 8;

    const int tid = threadIdx.x, lane = tid & 63, wid = tid >> 6;
    const int r15 = lane & 15, hi = lane >> 4;
    const int q0 = bx * 128 + wid * 16;
    const int brow = b * SS;

    __shared__ short Ks[2][128 * 64];    // XOR-swizzled within 128B rows, double-buffered
    __shared__ short Vt[2][64 * 136];    // [dh][136] transposed V, perm'd cols, +8 pad, dbuf

    const short* Kbase = K + (size_t)brow * SD + h * SDH;
    const short* Vbase = V + (size_t)brow * SD + h * SDH;
    const ull2* mrow_p = (const ull2*)(mbits + (size_t)(brow + q0 + r15) * (SS / 64));

    // Q fragments in registers (already scaled into log2 domain)
    short8 qF[2];
#pragma unroll
    for (int kd = 0; kd < 2; ++kd)
        qF[kd] = *(const short8*)&Q[(size_t)(brow + q0 + r15) * SD + h * SDH + kd * 32 + hi * 8];

    // all-ones bf16 B fragment for the l-MFMA
    short8 onesF;
#pragma unroll
    for (int j = 0; j < 8; ++j) onesF[j] = (short)0x3F80;

    f32x4 o[4] = {};
    f32x4 lacc = {};                 // l in row-layout: lacc[r] = l(q = hi*4+r)

    // K staging: 1024 chunks of 16B (128 rows x 8), 2 per thread
    // V staging: 64 row-pairs x 8 col-groups; each thread packs 2 rows x 8 cols
    const int vp = tid & 63, vc0 = (tid >> 6) * 8;
    const int k2 = 2 * vp;           // 0..126
    const int vcol = (k2 & 96) | ((k2 & 12) << 1) | ((k2 & 16) >> 2) | (k2 & 3);
    const int sh4 = hi * 4;

    // ---- prologue: stage tile-pair 0 into buffer 0 ----
#pragma unroll
    for (int c2 = 0; c2 < 2; ++c2) {
        int chBase = c2 * 512 + wid * 64;
        int ch = chBase + lane;
        int row = ch >> 3, c16 = ch & 7;
        gload_lds16(Kbase + (size_t)row * SD + ((c16 ^ (row & 7)) * 8), &Ks[0][chBase * 8]);
    }
    short8 va = *(const short8*)(Vbase + (size_t)k2 * SD + vc0);
    short8 vb2 = *(const short8*)(Vbase + (size_t)(k2 + 1) * SD + vc0);
    ull2 mb = mrow_p[0];
#pragma unroll
    for (int j = 0; j < 8; ++j) {
        uint32_t pk = (uint32_t)(uint16_t)va[j] | ((uint32_t)(uint16_t)vb2[j] << 16);
        *(uint32_t*)&Vt[0][(vc0 + j) * 136 + vcol] = pk;
    }

    const int NT = SS / 128;         // 16 iterations
    for (int t = 0; t < NT; ++t) {
        __syncthreads();                    // buf[cur] ready; buf[nxt] free
        const int cur = t & 1, nxt = cur ^ 1;
        const int tn = (t < NT - 1) ? t + 1 : t;   // clamped prefetch

        // ---- issue next-pair staging (latency hides under this pair's compute) ----
#pragma unroll
        for (int c2 = 0; c2 < 2; ++c2) {
            int chBase = c2 * 512 + wid * 64;
            int ch = chBase + lane;
            int row = ch >> 3, c16 = ch & 7;
            gload_lds16(Kbase + (size_t)(tn * 128 + row) * SD + ((c16 ^ (row & 7)) * 8),
                        &Ks[nxt][chBase * 8]);
        }
        va  = *(const short8*)(Vbase + (size_t)(tn * 128 + k2) * SD + vc0);
        vb2 = *(const short8*)(Vbase + (size_t)(tn * 128 + k2 + 1) * SD + vc0);
        ull2 mbn = mrow_p[tn];

        // ---- QK^T swapped: s[kc] holds raw scores for k = kc*16 + hi*4 + r, q = r15 ----
        f32x4 s[8] = {};
        __builtin_amdgcn_s_setprio(1);
#pragma unroll
        for (int kc = 0; kc < 8; ++kc) {
            int krow = kc * 16 + r15;
#pragma unroll
            for (int kd = 0; kd < 2; ++kd) {
                short8 kF = *(const short8*)&Ks[cur][krow * 64 + (((kd * 4 + hi) ^ (krow & 7)) * 8)];
                s[kc] = __builtin_amdgcn_mfma_f32_16x16x32_bf16(kF, qF[kd], s[kc], 0, 0, 0);
            }
        }
        __builtin_amdgcn_s_setprio(0);

        // ---- shift-free exp + mask-zero via sign-extend AND ----
        {
            unsigned w0 = (unsigned)mb[0], w1 = (unsigned)(mb[0] >> 32);
            unsigned w2 = (unsigned)mb[1], w3 = (unsigned)(mb[1] >> 32);
            unsigned hsh[8] = { w0 >> sh4, (w0 >> 16) >> sh4, w1 >> sh4, (w1 >> 16) >> sh4,
                                w2 >> sh4, (w2 >> 16) >> sh4, w3 >> sh4, (w3 >> 16) >> sh4 };
#pragma unroll
            for (int kc = 0; kc < 8; ++kc) {
                unsigned hh = hsh[kc];
#pragma unroll
                for (int r = 0; r < 4; ++r) {
                    float e;
                    asm("v_exp_f32 %0, %1" : "=v"(e) : "v"(s[kc][r]));
                    int m = ((int)(hh << (31 - r))) >> 31;       // 0 or -1
                    s[kc][r] = __uint_as_float(__float_as_uint(e) & (unsigned)m);
                }
            }
        }

        // ---- pF built IN-REGISTER (permuted contraction; no LDS, no cross-lane) ----
        short8 pF[4];
#pragma unroll
        for (int kf = 0; kf < 4; ++kf) {
            uint32_t w0, w1, w2, w3;
            asm("v_cvt_pk_bf16_f32 %0, %1, %2" : "=v"(w0) : "v"(s[2 * kf][0]),     "v"(s[2 * kf][1]));
            asm("v_cvt_pk_bf16_f32 %0, %1, %2" : "=v"(w1) : "v"(s[2 * kf][2]),     "v"(s[2 * kf][3]));
            asm("v_cvt_pk_bf16_f32 %0, %1, %2" : "=v"(w2) : "v"(s[2 * kf + 1][0]), "v"(s[2 * kf + 1][1]));
            asm("v_cvt_pk_bf16_f32 %0, %1, %2" : "=v"(w3) : "v"(s[2 * kf + 1][2]), "v"(s[2 * kf + 1][3]));
            uint4v t4 = { w0, w1, w2, w3 };
            pF[kf] = __builtin_bit_cast(short8, t4);
        }

        // ---- PV + l over 128 k: o[df] += P * V ; lacc += P * 1 ----
        __builtin_amdgcn_s_setprio(1);
#pragma unroll
        for (int df = 0; df < 4; ++df) {
#pragma unroll
            for (int kf = 0; kf < 4; ++kf) {
                short8 vF = *(const short8*)&Vt[cur][(df * 16 + r15) * 136 + kf * 32 + hi * 8];
                o[df] = __builtin_amdgcn_mfma_f32_16x16x32_bf16(pF[kf], vF, o[df], 0, 0, 0);
            }
        }
#pragma unroll
        for (int kf = 0; kf < 4; ++kf)
            lacc = __builtin_amdgcn_mfma_f32_16x16x32_bf16(pF[kf], onesF, lacc, 0, 0, 0);
        __builtin_amdgcn_s_setprio(0);

        // ---- write prefetched V into Vt[nxt] (after PV reads of Vt[cur]) ----
#pragma unroll
        for (int j = 0; j < 8; ++j) {
            uint32_t pk = (uint32_t)(uint16_t)va[j] | ((uint32_t)(uint16_t)vb2[j] << 16);
            *(uint32_t*)&Vt[nxt][(vc0 + j) * 136 + vcol] = pk;
        }
        mb = mbn;
    }

    // ---- epilogue: O = o / l (l already in row layout) ----
#pragma unroll
    for (int r = 0; r < 4; ++r) {
        float inv = 1.0f / lacc[r];
        size_t row = (size_t)(brow + q0 + hi * 4 + r);
#pragma unroll
        for (int df = 0; df < 4; ++df)
            O[row * SD + h * SDH + df * 16 + r15] = f2bf(o[df][r] * inv);
    }
}

// ---------------- host launcher ----------------
extern "C" void kernel_launch(void* const* d_in, const int* in_sizes, int n_in,
                              void* d_out, int out_size, void* d_ws, size_t ws_size,
                              hipStream_t stream) {
    const float* x  = (const float*)d_in[0];
    const int* mask = (const int*)d_in[1];
    const float* Wq = (const float*)d_in[2];
    const float* bq = (const float*)d_in[3];
    const float* Wk = (const float*)d_in[4];
    const float* bk = (const float*)d_in[5];
    const float* Wv = (const float*)d_in[6];
    const float* bv = (const float*)d_in[7];
    const float* Wo = (const float*)d_in[8];
    const float* bo = (const float*)d_in[9];
    float* out = (float*)d_out;

    char* ws = (char*)d_ws;
    size_t off = 0;
    auto alloc = [&](size_t bytes) { void* p = ws + off; off += (bytes + 255) & ~(size_t)255; return p; };

    short* xb  = (short*)alloc((size_t)SM * SD * 2);
    short* wqb = (short*)alloc((size_t)SD * SD * 2);
    short* wkb = (short*)alloc((size_t)SD * SD * 2);
    short* wvb = (short*)alloc((size_t)SD * SD * 2);
    short* wob = (short*)alloc((size_t)SD * SD * 2);
    short* Qb  = (short*)alloc((size_t)SM * SD * 2);
    short* Kb  = (short*)alloc((size_t)SM * SD * 2);
    short* Vb  = (short*)alloc((size_t)SM * SD * 2);
    short* AOb = (short*)alloc((size_t)SM * SD * 2);
    unsigned long long* mbits = (unsigned long long*)alloc((size_t)SB * SS * (SS / 64) * 8);

    prep_kernel<<<(NCVT + NMSK) / 256, 256, 0, stream>>>(
        x, Wq, Wk, Wv, Wo, mask, xb, wqb, wkb, wvb, wob, mbits);

    gemm_qkv_kernel<<<dim3(SD / 128, SM / 128, 3), 256, 0, stream>>>(
        xb, wqb, wkb, wvb, bq, bk, bv, Qb, Kb, Vb);

    attn_kernel<<<dim3(SS / 128, SH, SB), 512, 0, stream>>>(Qb, Kb, Vb, mbits, AOb);

    gemm_out_kernel<<<dim3(SD / 64, SM / 128), 256, 0, stream>>>(AOb, wob, bo, out);
}

// Round 17
// 130.650 us; speedup vs baseline: 1.0165x; 1.0165x over previous
//
#include <hip/hip_runtime.h>
#include <stdint.h>

// Problem constants: B=2, S=2048, D=1024, H=16, DH=64
#define SB 2
#define SS 2048
#define SD 1024
#define SH 16
#define SDH 64
#define SM (SB*SS)          // 4096 rows
// Q pre-scale: (1/sqrt(DH)) * log2(e) = 0.125 * 1.4426950408889634
#define QSCALE 0.18033688011112043f

typedef __attribute__((ext_vector_type(8))) short short8;
typedef __attribute__((ext_vector_type(4))) short short4v;
typedef __attribute__((ext_vector_type(4))) float f32x4;
typedef __attribute__((ext_vector_type(4))) float float4v;
typedef __attribute__((ext_vector_type(4))) uint32_t uint4v;
typedef __attribute__((ext_vector_type(2))) unsigned long long ull2;

__device__ static inline short f2bf(float f) {
    uint32_t u = __float_as_uint(f);
    u += 0x7fffu + ((u >> 16) & 1u);   // RNE
    return (short)(u >> 16);
}

__device__ static inline void gload_lds16(const void* g, void* l) {
    __builtin_amdgcn_global_load_lds(
        (__attribute__((address_space(1))) void*)g,
        (__attribute__((address_space(3))) void*)l,
        16, 0, 0);
}

// ---------------- fused prep: fp32->bf16 convert (x + 4 weights) AND mask bit-pack ----------------
#define NX4 (SM*SD/4)      // 1048576 float4 in x
#define NW4 (SD*SD/4)      // 262144 float4 per weight
#define NCVT (NX4 + 4*NW4) // 2097152 cvt threads
#define NMSK (SB*SS*SS)    // 8388608 mask threads
__global__ void prep_kernel(const float* __restrict__ x,
                            const float* __restrict__ Wq, const float* __restrict__ Wk,
                            const float* __restrict__ Wv, const float* __restrict__ Wo,
                            const int* __restrict__ mask,
                            short* __restrict__ xb,
                            short* __restrict__ wqb, short* __restrict__ wkb,
                            short* __restrict__ wvb, short* __restrict__ wob,
                            unsigned long long* __restrict__ bits) {
    unsigned i = blockIdx.x * 256u + threadIdx.x;
    if (i < NCVT) {
        const float* src; short* dst; unsigned idx;
        if (i < NX4) { src = x; dst = xb; idx = i; }
        else {
            unsigned j = i - NX4;
            unsigned sel = j >> 18;               // NW4 = 2^18
            idx = j & (NW4 - 1);
            src = (sel == 0) ? Wq : (sel == 1) ? Wk : (sel == 2) ? Wv : Wo;
            dst = (sel == 0) ? wqb : (sel == 1) ? wkb : (sel == 2) ? wvb : wob;
        }
        float4v v = *(const float4v*)(src + (size_t)idx * 4);
        short4v o;
        o[0] = f2bf(v[0]); o[1] = f2bf(v[1]); o[2] = f2bf(v[2]); o[3] = f2bf(v[3]);
        *(short4v*)(dst + (size_t)idx * 4) = o;
    } else {
        unsigned j = i - NCVT;                    // wave-aligned region (NCVT % 64 == 0)
        int pred = mask[j] != 0;
        unsigned long long bb = __ballot(pred);
        if ((threadIdx.x & 63u) == 0u) bits[j >> 6] = bb;
    }
}

// ---------------- QKV GEMM: 128x128 tile, BK=32, 3-buffer counted-vmcnt pipeline ----------------
// stage(t+1) -> s_waitcnt vmcnt(4) lgkmcnt(0) -> s_barrier -> read buf[cur].
// 3 buffers: stage(t) writes buf[(t+1)%3], last read at t-2, drained before barrier(t-1). Safe.
__global__ __launch_bounds__(256, 3) void gemm_qkv_kernel(
    const short* __restrict__ A,
    const short* __restrict__ W0, const short* __restrict__ W1, const short* __restrict__ W2,
    const float* __restrict__ b0, const float* __restrict__ b1, const float* __restrict__ b2,
    short* __restrict__ O0, short* __restrict__ O1, short* __restrict__ O2) {
    // grid (8,32,3) = 768 blocks; bijective XCD swizzle: each XCD gets 96 consecutive logicals
    unsigned flat = blockIdx.x + (blockIdx.y << 3) + (blockIdx.z << 8);
    unsigned swz = (flat & 7u) * 96u + (flat >> 3);
    const int bx = swz & 7, by = (swz >> 3) & 31, bz = swz >> 8;

    const short* W = (bz == 0) ? W0 : (bz == 1) ? W1 : W2;
    const float* bias = (bz == 0) ? b0 : (bz == 1) ? b1 : b2;
    short* C = (bz == 0) ? O0 : (bz == 1) ? O1 : O2;
    const float scale = (bz == 0) ? QSCALE : 1.0f;
    const int rowBase = by * 128, colBase = bx * 128;
    const int K = SD, N = SD;

    __shared__ short As[3][128 * 32];
    __shared__ short Bs[3][128 * 32];
    const int tid = threadIdx.x, lane = tid & 63, wid = tid >> 6;
    const int r15 = lane & 15, hi = lane >> 4;
    const int wr = wid >> 1, wc = wid & 1;

    const int chBase0 = wid * 64, chBase1 = 256 + wid * 64;
    const int ch0 = chBase0 + lane, ch1 = chBase1 + lane;
    const short* aP0 = A + (size_t)(rowBase + (ch0 >> 2)) * K + (ch0 & 3) * 8;
    const short* aP1 = A + (size_t)(rowBase + (ch1 >> 2)) * K + (ch1 & 3) * 8;
    const short* bP0 = W + (size_t)(colBase + (ch0 >> 2)) * K + (ch0 & 3) * 8;
    const short* bP1 = W + (size_t)(colBase + (ch1 >> 2)) * K + (ch1 & 3) * 8;

    // prologue: stage tile 0 into buffer 0
    gload_lds16(aP0, &As[0][chBase0 * 8]);
    gload_lds16(aP1, &As[0][chBase1 * 8]);
    gload_lds16(bP0, &Bs[0][chBase0 * 8]);
    gload_lds16(bP1, &Bs[0][chBase1 * 8]);

    f32x4 acc[4][4] = {};
    const int NIT = K / 32;
    int cur = 0, nb = 1;

    for (int it = 0; it < NIT; ++it) {
        if (it + 1 < NIT) {
            int kt = (it + 1) * 32;
            gload_lds16(aP0 + kt, &As[nb][chBase0 * 8]);
            gload_lds16(aP1 + kt, &As[nb][chBase1 * 8]);
            gload_lds16(bP0 + kt, &Bs[nb][chBase0 * 8]);
            gload_lds16(bP1 + kt, &Bs[nb][chBase1 * 8]);
            asm volatile("s_waitcnt vmcnt(4) lgkmcnt(0)\ns_barrier" ::: "memory");
        } else {
            asm volatile("s_waitcnt vmcnt(0) lgkmcnt(0)\ns_barrier" ::: "memory");
        }
        __builtin_amdgcn_sched_barrier(0);

        short8 aF[4], bF[4];
#pragma unroll
        for (int mi = 0; mi < 4; ++mi)
            aF[mi] = *(const short8*)&As[cur][(wr * 64 + mi * 16 + r15) * 32 + hi * 8];
#pragma unroll
        for (int ni = 0; ni < 4; ++ni)
            bF[ni] = *(const short8*)&Bs[cur][(wc * 64 + ni * 16 + r15) * 32 + hi * 8];

        __builtin_amdgcn_s_setprio(1);
#pragma unroll
        for (int mi = 0; mi < 4; ++mi)
#pragma unroll
            for (int ni = 0; ni < 4; ++ni)
                acc[mi][ni] = __builtin_amdgcn_mfma_f32_16x16x32_bf16(aF[mi], bF[ni], acc[mi][ni], 0, 0, 0);
        __builtin_amdgcn_s_setprio(0);

        cur = (cur + 1 == 3) ? 0 : cur + 1;
        nb  = (nb + 1 == 3) ? 0 : nb + 1;
    }

#pragma unroll
    for (int ni = 0; ni < 4; ++ni) {
        int col = colBase + wc * 64 + ni * 16 + r15;
        float bv = bias[col];
#pragma unroll
        for (int mi = 0; mi < 4; ++mi) {
#pragma unroll
            for (int r = 0; r < 4; ++r) {
                int row = rowBase + wr * 64 + mi * 16 + hi * 4 + r;
                C[(size_t)row * N + col] = f2bf((acc[mi][ni][r] + bv) * scale);
            }
        }
    }
}

// ---------------- out-proj GEMM: 128x64 tile, 3-buffer counted-vmcnt pipeline ----------------
__global__ __launch_bounds__(256, 2) void gemm_out_kernel(
    const short* __restrict__ A, const short* __restrict__ W,
    const float* __restrict__ bias, float* __restrict__ C) {
    unsigned flat = blockIdx.x + (blockIdx.y << 4);
    unsigned swz = (flat & 7u) * 64u + (flat >> 3);
    const int rowBase = ((swz >> 4) & 31) * 128, colBase = (swz & 15) * 64;
    const int K = SD, N = SD;

    __shared__ short As[3][128 * 32];
    __shared__ short Bs[3][64 * 32];
    const int tid = threadIdx.x, lane = tid & 63, wid = tid >> 6;
    const int r15 = lane & 15, hi = lane >> 4;

    const int chBase0 = wid * 64, chBase1 = 256 + wid * 64;
    const int ch0 = chBase0 + lane, ch1 = chBase1 + lane;
    const short* aP0 = A + (size_t)(rowBase + (ch0 >> 2)) * K + (ch0 & 3) * 8;
    const short* aP1 = A + (size_t)(rowBase + (ch1 >> 2)) * K + (ch1 & 3) * 8;
    const short* bP0 = W + (size_t)(colBase + (ch0 >> 2)) * K + (ch0 & 3) * 8;

    gload_lds16(aP0, &As[0][chBase0 * 8]);
    gload_lds16(aP1, &As[0][chBase1 * 8]);
    gload_lds16(bP0, &Bs[0][chBase0 * 8]);

    f32x4 acc[2][4] = {};
    const int NIT = K / 32;
    int cur = 0, nb = 1;

    for (int it = 0; it < NIT; ++it) {
        if (it + 1 < NIT) {
            int kt = (it + 1) * 32;
            gload_lds16(aP0 + kt, &As[nb][chBase0 * 8]);
            gload_lds16(aP1 + kt, &As[nb][chBase1 * 8]);
            gload_lds16(bP0 + kt, &Bs[nb][chBase0 * 8]);
            asm volatile("s_waitcnt vmcnt(3) lgkmcnt(0)\ns_barrier" ::: "memory");
        } else {
            asm volatile("s_waitcnt vmcnt(0) lgkmcnt(0)\ns_barrier" ::: "memory");
        }
        __builtin_amdgcn_sched_barrier(0);

        short8 aF[2], bF[4];
#pragma unroll
        for (int mi = 0; mi < 2; ++mi)
            aF[mi] = *(const short8*)&As[cur][(wid * 32 + mi * 16 + r15) * 32 + hi * 8];
#pragma unroll
        for (int ni = 0; ni < 4; ++ni)
            bF[ni] = *(const short8*)&Bs[cur][(ni * 16 + r15) * 32 + hi * 8];

        __builtin_amdgcn_s_setprio(1);
#pragma unroll
        for (int mi = 0; mi < 2; ++mi)
#pragma unroll
            for (int ni = 0; ni < 4; ++ni)
                acc[mi][ni] = __builtin_amdgcn_mfma_f32_16x16x32_bf16(aF[mi], bF[ni], acc[mi][ni], 0, 0, 0);
        __builtin_amdgcn_s_setprio(0);

        cur = (cur + 1 == 3) ? 0 : cur + 1;
        nb  = (nb + 1 == 3) ? 0 : nb + 1;
    }

#pragma unroll
    for (int ni = 0; ni < 4; ++ni) {
        int col = colBase + ni * 16 + r15;
        float bv = bias[col];
#pragma unroll
        for (int mi = 0; mi < 2; ++mi) {
#pragma unroll
            for (int r = 0; r < 4; ++r) {
                int row = rowBase + wid * 32 + mi * 16 + hi * 4 + r;
                C[(size_t)row * N + col] = acc[mi][ni][r] + bv;
            }
        }
    }
}

// ---------------- flash attention (R12: KVBLK=128, 16q/wave, 2 blocks/CU) ----------------
// grid (S/128, H, B) = 512 blocks (2/CU); block 512 = 8 waves; wave owns 16 q rows.
// KV processed 128 rows per iteration (16 loop iters, 16 barriers). Shift-free softmax,
// sign-extend masking, in-register P via permuted contraction (V cols at
// c(k)=(k&96)|((k&12)<<1)|((k&16)>>2)|(k&3)), XCD swizzle for L2-hot K/V.
__global__ __launch_bounds__(512, 4) void attn_kernel(
    const short* __restrict__ Q, const short* __restrict__ K, const short* __restrict__ V,
    const unsigned long long* __restrict__ mbits, short* __restrict__ O) {
    // grid (16,16,2) = 512 blocks; bijective swizzle: XCD k gets 64 consecutive logicals
    unsigned flat = blockIdx.x + (blockIdx.y << 4) + (blockIdx.z << 8);
    unsigned swz = (flat & 7u) * 64u + (flat >> 3);
    const int bx = swz & 15, h = (swz >> 4) & 15, b = swz >> 8;

    const int tid = threadIdx.x, lane = tid & 63, wid = tid >> 6;
    const int r15 = lane & 15, hi = lane >> 4;
    const int q0 = bx * 128 + wid * 16;
    const int brow = b * SS;

    __shared__ short Ks[2][128 * 64];    // XOR-swizzled within 128B rows, double-buffered
    __shared__ short Vt[2][64 * 136];    // [dh][136] transposed V, perm'd cols, +8 pad, dbuf

    const short* Kbase = K + (size_t)brow * SD + h * SDH;
    const short* Vbase = V + (size_t)brow * SD + h * SDH;
    const ull2* mrow_p = (const ull2*)(mbits + (size_t)(brow + q0 + r15) * (SS / 64));

    // Q fragments in registers (already scaled into log2 domain)
    short8 qF[2];
#pragma unroll
    for (int kd = 0; kd < 2; ++kd)
        qF[kd] = *(const short8*)&Q[(size_t)(brow + q0 + r15) * SD + h * SDH + kd * 32 + hi * 8];

    // all-ones bf16 B fragment for the l-MFMA
    short8 onesF;
#pragma unroll
    for (int j = 0; j < 8; ++j) onesF[j] = (short)0x3F80;

    f32x4 o[4] = {};
    f32x4 lacc = {};                 // l in row-layout: lacc[r] = l(q = hi*4+r)

    // K staging: 1024 chunks of 16B (128 rows x 8), 2 per thread
    // V staging: 64 row-pairs x 8 col-groups; each thread packs 2 rows x 8 cols
    const int vp = tid & 63, vc0 = (tid >> 6) * 8;
    const int k2 = 2 * vp;           // 0..126
    const int vcol = (k2 & 96) | ((k2 & 12) << 1) | ((k2 & 16) >> 2) | (k2 & 3);
    const int sh4 = hi * 4;

    // ---- prologue: stage tile-pair 0 into buffer 0 ----
#pragma unroll
    for (int c2 = 0; c2 < 2; ++c2) {
        int chBase = c2 * 512 + wid * 64;
        int ch = chBase + lane;
        int row = ch >> 3, c16 = ch & 7;
        gload_lds16(Kbase + (size_t)row * SD + ((c16 ^ (row & 7)) * 8), &Ks[0][chBase * 8]);
    }
    short8 va = *(const short8*)(Vbase + (size_t)k2 * SD + vc0);
    short8 vb2 = *(const short8*)(Vbase + (size_t)(k2 + 1) * SD + vc0);
    ull2 mb = mrow_p[0];
#pragma unroll
    for (int j = 0; j < 8; ++j) {
        uint32_t pk = (uint32_t)(uint16_t)va[j] | ((uint32_t)(uint16_t)vb2[j] << 16);
        *(uint32_t*)&Vt[0][(vc0 + j) * 136 + vcol] = pk;
    }

    const int NT = SS / 128;         // 16 iterations
    for (int t = 0; t < NT; ++t) {
        __syncthreads();                    // buf[cur] ready; buf[nxt] free
        const int cur = t & 1, nxt = cur ^ 1;
        const int tn = (t < NT - 1) ? t + 1 : t;   // clamped prefetch

        // ---- issue next-pair staging (latency hides under this pair's compute) ----
#pragma unroll
        for (int c2 = 0; c2 < 2; ++c2) {
            int chBase = c2 * 512 + wid * 64;
            int ch = chBase + lane;
            int row = ch >> 3, c16 = ch & 7;
            gload_lds16(Kbase + (size_t)(tn * 128 + row) * SD + ((c16 ^ (row & 7)) * 8),
                        &Ks[nxt][chBase * 8]);
        }
        va  = *(const short8*)(Vbase + (size_t)(tn * 128 + k2) * SD + vc0);
        vb2 = *(const short8*)(Vbase + (size_t)(tn * 128 + k2 + 1) * SD + vc0);
        ull2 mbn = mrow_p[tn];

        // ---- QK^T swapped: s[kc] holds raw scores for k = kc*16 + hi*4 + r, q = r15 ----
        f32x4 s[8] = {};
        __builtin_amdgcn_s_setprio(1);
#pragma unroll
        for (int kc = 0; kc < 8; ++kc) {
            int krow = kc * 16 + r15;
#pragma unroll
            for (int kd = 0; kd < 2; ++kd) {
                short8 kF = *(const short8*)&Ks[cur][krow * 64 + (((kd * 4 + hi) ^ (krow & 7)) * 8)];
                s[kc] = __builtin_amdgcn_mfma_f32_16x16x32_bf16(kF, qF[kd], s[kc], 0, 0, 0);
            }
        }
        __builtin_amdgcn_s_setprio(0);

        // ---- shift-free exp + mask-zero via sign-extend AND ----
        {
            unsigned w0 = (unsigned)mb[0], w1 = (unsigned)(mb[0] >> 32);
            unsigned w2 = (unsigned)mb[1], w3 = (unsigned)(mb[1] >> 32);
            unsigned hsh[8] = { w0 >> sh4, (w0 >> 16) >> sh4, w1 >> sh4, (w1 >> 16) >> sh4,
                                w2 >> sh4, (w2 >> 16) >> sh4, w3 >> sh4, (w3 >> 16) >> sh4 };
#pragma unroll
            for (int kc = 0; kc < 8; ++kc) {
                unsigned hh = hsh[kc];
#pragma unroll
                for (int r = 0; r < 4; ++r) {
                    float e;
                    asm("v_exp_f32 %0, %1" : "=v"(e) : "v"(s[kc][r]));
                    int m = ((int)(hh << (31 - r))) >> 31;       // 0 or -1
                    s[kc][r] = __uint_as_float(__float_as_uint(e) & (unsigned)m);
                }
            }
        }

        // ---- pF built IN-REGISTER (permuted contraction; no LDS, no cross-lane) ----
        short8 pF[4];
#pragma unroll
        for (int kf = 0; kf < 4; ++kf) {
            uint32_t w0, w1, w2, w3;
            asm("v_cvt_pk_bf16_f32 %0, %1, %2" : "=v"(w0) : "v"(s[2 * kf][0]),     "v"(s[2 * kf][1]));
            asm("v_cvt_pk_bf16_f32 %0, %1, %2" : "=v"(w1) : "v"(s[2 * kf][2]),     "v"(s[2 * kf][3]));
            asm("v_cvt_pk_bf16_f32 %0, %1, %2" : "=v"(w2) : "v"(s[2 * kf + 1][0]), "v"(s[2 * kf + 1][1]));
            asm("v_cvt_pk_bf16_f32 %0, %1, %2" : "=v"(w3) : "v"(s[2 * kf + 1][2]), "v"(s[2 * kf + 1][3]));
            uint4v t4 = { w0, w1, w2, w3 };
            pF[kf] = __builtin_bit_cast(short8, t4);
        }

        // ---- PV + l over 128 k: o[df] += P * V ; lacc += P * 1 ----
        __builtin_amdgcn_s_setprio(1);
#pragma unroll
        for (int df = 0; df < 4; ++df) {
#pragma unroll
            for (int kf = 0; kf < 4; ++kf) {
                short8 vF = *(const short8*)&Vt[cur][(df * 16 + r15) * 136 + kf * 32 + hi * 8];
                o[df] = __builtin_amdgcn_mfma_f32_16x16x32_bf16(pF[kf], vF, o[df], 0, 0, 0);
            }
        }
#pragma unroll
        for (int kf = 0; kf < 4; ++kf)
            lacc = __builtin_amdgcn_mfma_f32_16x16x32_bf16(pF[kf], onesF, lacc, 0, 0, 0);
        __builtin_amdgcn_s_setprio(0);

        // ---- write prefetched V into Vt[nxt] (after PV reads of Vt[cur]) ----
#pragma unroll
        for (int j = 0; j < 8; ++j) {
            uint32_t pk = (uint32_t)(uint16_t)va[j] | ((uint32_t)(uint16_t)vb2[j] << 16);
            *(uint32_t*)&Vt[nxt][(vc0 + j) * 136 + vcol] = pk;
        }
        mb = mbn;
    }

    // ---- epilogue: O = o / l (l already in row layout) ----
#pragma unroll
    for (int r = 0; r < 4; ++r) {
        float inv = 1.0f / lacc[r];
        size_t row = (size_t)(brow + q0 + hi * 4 + r);
#pragma unroll
        for (int df = 0; df < 4; ++df)
            O[row * SD + h * SDH + df * 16 + r15] = f2bf(o[df][r] * inv);
    }
}

// ---------------- host launcher ----------------
extern "C" void kernel_launch(void* const* d_in, const int* in_sizes, int n_in,
                              void* d_out, int out_size, void* d_ws, size_t ws_size,
                              hipStream_t stream) {
    const float* x  = (const float*)d_in[0];
    const int* mask = (const int*)d_in[1];
    const float* Wq = (const float*)d_in[2];
    const float* bq = (const float*)d_in[3];
    const float* Wk = (const float*)d_in[4];
    const float* bk = (const float*)d_in[5];
    const float* Wv = (const float*)d_in[6];
    const float* bv = (const float*)d_in[7];
    const float* Wo = (const float*)d_in[8];
    const float* bo = (const float*)d_in[9];
    float* out = (float*)d_out;

    char* ws = (char*)d_ws;
    size_t off = 0;
    auto alloc = [&](size_t bytes) { void* p = ws + off; off += (bytes + 255) & ~(size_t)255; return p; };

    short* xb  = (short*)alloc((size_t)SM * SD * 2);
    short* wqb = (short*)alloc((size_t)SD * SD * 2);
    short* wkb = (short*)alloc((size_t)SD * SD * 2);
    short* wvb = (short*)alloc((size_t)SD * SD * 2);
    short* wob = (short*)alloc((size_t)SD * SD * 2);
    short* Qb  = (short*)alloc((size_t)SM * SD * 2);
    short* Kb  = (short*)alloc((size_t)SM * SD * 2);
    short* Vb  = (short*)alloc((size_t)SM * SD * 2);
    short* AOb = (short*)alloc((size_t)SM * SD * 2);
    unsigned long long* mbits = (unsigned long long*)alloc((size_t)SB * SS * (SS / 64) * 8);

    prep_kernel<<<(NCVT + NMSK) / 256, 256, 0, stream>>>(
        x, Wq, Wk, Wv, Wo, mask, xb, wqb, wkb, wvb, wob, mbits);

    gemm_qkv_kernel<<<dim3(SD / 128, SM / 128, 3), 256, 0, stream>>>(
        xb, wqb, wkb, wvb, bq, bk, bv, Qb, Kb, Vb);

    attn_kernel<<<dim3(SS / 128, SH, SB), 512, 0, stream>>>(Qb, Kb, Vb, mbits, AOb);

    gemm_out_kernel<<<dim3(SD / 64, SM / 128), 256, 0, stream>>>(AOb, wob, bo, out);
}